// Round 2
// 289.752 us; speedup vs baseline: 1.2201x; 1.2201x over previous
//
#include <hip/hip_runtime.h>
#include <stdint.h>

typedef unsigned short U16;
typedef unsigned int   U32;
typedef __attribute__((ext_vector_type(8))) short short8;   // 8 bf16 = 4 VGPRs (MFMA A/B frag)
typedef __attribute__((ext_vector_type(4))) float floatx4;  // MFMA C/D frag

#define HW 3136   // 56*56

__device__ __forceinline__ U16 f2b(float f){
    union { float f; unsigned int i; } v; v.f = f;
    unsigned int u = (v.i + 0x7FFFu + ((v.i >> 16) & 1u)) >> 16;  // RNE
    return (U16)u;
}
// load 8 consecutive fp32, round to bf16, return as MFMA 8x-bf16 fragment
__device__ __forceinline__ short8 pack8(const float* p){
    float4 a = *reinterpret_cast<const float4*>(p);
    float4 b = *reinterpret_cast<const float4*>(p + 4);
    short8 r;
    r[0]=(short)f2b(a.x); r[1]=(short)f2b(a.y); r[2]=(short)f2b(a.z); r[3]=(short)f2b(a.w);
    r[4]=(short)f2b(b.x); r[5]=(short)f2b(b.y); r[6]=(short)f2b(b.z); r[7]=(short)f2b(b.w);
    return r;
}

// ---------------------------------------------------------------------------
// k_pre: fold BN into fp32 scale/shift; transpose+convert w2 (fp32) ->
// bf16 [g][tap][oc 32][ic 32].
// bn layout (fp32): [0:128) s1 [128:256) sh1 [256:384) s2 [384:512) sh2
//                   [512:1024) s3 [1024:1536) sh3
// ---------------------------------------------------------------------------
__global__ void k_pre(const float* __restrict__ w2,
                      const float* g1, const float* b1, const float* m1, const float* v1,
                      const float* g2, const float* b2, const float* m2, const float* v2,
                      const float* g3, const float* b3, const float* m3, const float* v3,
                      U16* __restrict__ w2t, float* __restrict__ bn){
  int i = blockIdx.x * 256 + threadIdx.x;
  if (i < 4*9*32*32) {
    int ic  = i & 31;
    int oc  = (i >> 5) & 31;
    int gt  = i >> 10;          // g*9 + tap
    int g_  = gt / 9, tap = gt % 9;
    w2t[i] = f2b(w2[((g_*32 + oc)*32 + ic)*9 + tap]);
  } else {
    int j = i - 4*9*32*32;
    if (j >= 768) return;
    const float *gp, *bp, *mp, *vp; int c, so, sho;
    if (j < 128)      { c = j;       gp=g1; bp=b1; mp=m1; vp=v1; so = 0;   sho = 128;  }
    else if (j < 256) { c = j - 128; gp=g2; bp=b2; mp=m2; vp=v2; so = 256; sho = 384;  }
    else              { c = j - 256; gp=g3; bp=b3; mp=m3; vp=v3; so = 512; sho = 1024; }
    float s = gp[c] / sqrtf(vp[c] + 1e-5f);
    bn[so + c]  = s;
    bn[sho + c] = bp[c] - mp[c] * s;
  }
}

// ---------------------------------------------------------------------------
// k_conv1: t1 = mask * relu(bn1(conv1x1_g(mask * x)))   (512 -> 128, G=4)
// STRIP version: block = (mh, g, b), 256 thr / 4 waves, 8x56 = 448 px strip.
// Uniform over mask (gate input at staging, gate output in epilogue) ->
// fully-coalesced 1792B-contiguous strip reads of x.
// K-chunked (4 x 32 ic) LDS staging: [32 ic][456] bf16 (29 KB).
// ---------------------------------------------------------------------------
__global__ __launch_bounds__(256) void k_conv1(const float* __restrict__ x,
        const float* __restrict__ mask, const float* __restrict__ w1,
        const float* __restrict__ bn, U16* __restrict__ t1){
  const int t = threadIdx.x;
  const int lane = t & 63, wave = t >> 6;
  const int quad = lane >> 4, l15 = lane & 15;
  const int b = blockIdx.z, g = blockIdx.y, mh = blockIdx.x;
  const int h0 = mh*8, wbase = wave*112;
  __shared__ float mk[7];
  __shared__ __align__(16) U16 xs[32*456];
  if (t < 7) mk[t] = mask[((b*4 + g)*7 + mh)*7 + t];
  const float* xg = x + (size_t)(b*512 + g*128)*HW + h0*56;
  U16* t1g = t1 + (size_t)(b*128 + g*32)*HW + h0*56;

  // A fragments: w1 fp32 [oc(g*32..)][ic 128]
  const float* wg = w1 + (size_t)(g*32)*128;
  short8 afr[2][4];
  #pragma unroll
  for (int oct = 0; oct < 2; ++oct)
    #pragma unroll
    for (int ks = 0; ks < 4; ++ks)
      afr[oct][ks] = pack8(wg + (oct*16 + l15)*128 + ks*32 + quad*8);

  floatx4 acc[2][7] = {};
  #pragma unroll
  for (int ch = 0; ch < 4; ++ch){
    __syncthreads();   // ch=0: guards mk; ch>0: guards xs reuse
    #pragma unroll
    for (int k = 0; k < 14; ++k){
      int idx = k*256 + t;                 // 3584 float4 = 32 ic x 112
      int ic = idx / 112, f = idx - ic*112;
      int px = f*4;                        // 4 cols, never crosses an 8-col cell
      float4 v = *reinterpret_cast<const float4*>(xg + (size_t)(ch*32 + ic)*HW + px);
      float m = mk[(px % 56) >> 3];
      U32 lo = (U32)f2b(v.x*m) | ((U32)f2b(v.y*m) << 16);
      U32 hi = (U32)f2b(v.z*m) | ((U32)f2b(v.w*m) << 16);
      *reinterpret_cast<uint2*>(&xs[ic*456 + px]) = make_uint2(lo, hi);
    }
    __syncthreads();
    #pragma unroll
    for (int pxt = 0; pxt < 7; ++pxt){
      short8 bfr;
      #pragma unroll
      for (int j = 0; j < 8; ++j)
        bfr[j] = (short)xs[(quad*8 + j)*456 + wbase + pxt*16 + l15];
      acc[0][pxt] = __builtin_amdgcn_mfma_f32_16x16x32_bf16(afr[0][ch], bfr, acc[0][pxt], 0,0,0);
      acc[1][pxt] = __builtin_amdgcn_mfma_f32_16x16x32_bf16(afr[1][ch], bfr, acc[1][pxt], 0,0,0);
    }
  }
  #pragma unroll
  for (int oct = 0; oct < 2; ++oct)
    #pragma unroll
    for (int reg = 0; reg < 4; ++reg){
      int oc = oct*16 + quad*4 + reg;
      float sc = bn[g*32 + oc], sh = bn[128 + g*32 + oc];
      #pragma unroll
      for (int pxt = 0; pxt < 7; ++pxt){
        int px = wbase + pxt*16 + l15;
        float y = fmaxf(sc*acc[oct][pxt][reg] + sh, 0.0f) * mk[(px % 56) >> 3];
        t1g[(size_t)oc*HW + px] = f2b(y);  // masked cells: exact 0
      }
    }
}

// ---------------------------------------------------------------------------
// k_conv2: t2 = mask * relu(bn2(conv3x3_g(t1)))   (128 -> 128, G=4, pad 1)
// STRIP version, uniform over mask (t1 already input-gated; output gated).
// LDS: [32 ic][10 r][72 c] bf16, data cols at 8..63, halo cols 7 and 64.
// Writes t2 everywhere (exact zeros in masked cells) -> conv3 is uniform.
// BUGFIX vs last round: halo zeroing has 320 entries but only 256 threads —
// must stride the loop, else ic>=26 halo cols held stale LDS garbage.
// ---------------------------------------------------------------------------
__global__ __launch_bounds__(256) void k_conv2(const U16* __restrict__ t1,
        const float* __restrict__ mask, const U16* __restrict__ w2t,
        const float* __restrict__ bn, U16* __restrict__ t2){
  const int t = threadIdx.x;
  const int lane = t & 63, wave = t >> 6;
  const int quad = lane >> 4, l15 = lane & 15;
  const int b = blockIdx.z, g = blockIdx.y, mh = blockIdx.x;
  const int h0 = mh*8;
  __shared__ float mk[7];
  __shared__ __align__(16) U16 s[32*720];
  if (t < 7) mk[t] = mask[((b*4 + g)*7 + mh)*7 + t];
  #pragma unroll
  for (int e = t; e < 320; e += 256){      // zero halo cols (c=-1, c=56), ALL 320
    int ic = e / 10, r = e - ic*10;
    s[(ic*10 + r)*72 + 7]  = 0;
    s[(ic*10 + r)*72 + 64] = 0;
  }
  const U16* tg = t1 + (size_t)(b*128 + g*32)*HW;
  #pragma unroll
  for (int k = 0; k < 9; ++k){
    int idx = k*256 + t;                   // 2240 uint4 = 32 ic x 10 r x 7 seg
    if (idx < 2240){
      int ic = idx / 70, rem = idx - ic*70;
      int r = rem / 7, seg = rem - r*7;
      int hh = h0 - 1 + r;
      uint4 v = make_uint4(0,0,0,0);
      if (hh >= 0 && hh < 56)
        v = *reinterpret_cast<const uint4*>(tg + (size_t)ic*HW + hh*56 + seg*8);
      *reinterpret_cast<uint4*>(&s[(ic*10 + r)*72 + 8 + seg*8]) = v;
    }
  }
  __syncthreads();
  const U16* wg = w2t + g*9*32*32;         // bf16 [tap][oc][ic]
  floatx4 acc[2][7] = {};
  #pragma unroll
  for (int kh = 0; kh < 3; ++kh){
    const int lr = wave*2 + (l15 >> 3) + kh;       // 0..9
    #pragma unroll
    for (int kw = 0; kw < 3; ++kw){
      int tap = kh*3 + kw;
      short8 a0 = *reinterpret_cast<const short8*>(wg + (tap*32 +      l15)*32 + quad*8);
      short8 a1 = *reinterpret_cast<const short8*>(wg + (tap*32 + 16 + l15)*32 + quad*8);
      #pragma unroll
      for (int pxt = 0; pxt < 7; ++pxt){
        int lc = 7 + pxt*8 + (l15 & 7) + kw;       // global col + 8 + (kw-1)
        short8 bfr;
        #pragma unroll
        for (int j = 0; j < 8; ++j)
          bfr[j] = (short)s[((quad*8 + j)*10 + lr)*72 + lc];
        acc[0][pxt] = __builtin_amdgcn_mfma_f32_16x16x32_bf16(a0, bfr, acc[0][pxt], 0,0,0);
        acc[1][pxt] = __builtin_amdgcn_mfma_f32_16x16x32_bf16(a1, bfr, acc[1][pxt], 0,0,0);
      }
    }
  }
  U16* og = t2 + (size_t)(b*128 + g*32)*HW + h0*56;
  const int pr = wave*2 + (l15 >> 3);
  #pragma unroll
  for (int oct = 0; oct < 2; ++oct)
    #pragma unroll
    for (int reg = 0; reg < 4; ++reg){
      int oc = oct*16 + quad*4 + reg;
      float sc = bn[256 + g*32 + oc], sh = bn[384 + g*32 + oc];
      #pragma unroll
      for (int pxt = 0; pxt < 7; ++pxt){
        float y = fmaxf(sc*acc[oct][pxt][reg] + sh, 0.0f) * mk[pxt];
        og[oc*HW + pr*56 + pxt*8 + (l15 & 7)] = f2b(y);   // masked: exact 0
      }
    }
}

// ---------------------------------------------------------------------------
// k_conv3: out = relu(bn3(conv1x1_g(t2)) + x)   (128 -> 512, G=4), fp32 out.
// STRIP version, fully uniform: t2 is exact 0 in masked cells, so
// relu(sc*0 + sh3 + x) == reference masked path. Residual reads/writes are
// aligned 64B segments (16 lanes x 4B consecutive).
// ---------------------------------------------------------------------------
__global__ __launch_bounds__(256) void k_conv3(const U16* __restrict__ t2,
        const float* __restrict__ x, const float* __restrict__ w3,
        const float* __restrict__ bn, float* __restrict__ out){
  const int t = threadIdx.x;
  const int lane = t & 63, wave = t >> 6;
  const int quad = lane >> 4, l15 = lane & 15;
  const int b = blockIdx.z, g = blockIdx.y, mh = blockIdx.x;
  const int h0 = mh*8, wbase = wave*112;
  __shared__ __align__(16) U16 xs[32*456];
  const U16* tg = t2 + (size_t)(b*128 + g*32)*HW + h0*56;
  #pragma unroll
  for (int k = 0; k < 7; ++k){
    int idx = k*256 + t;                   // 1792 uint4 = 32 ic x 56 seg
    int ic = idx / 56, seg = idx - ic*56;
    *reinterpret_cast<uint4*>(&xs[ic*456 + seg*8]) =
        *reinterpret_cast<const uint4*>(tg + (size_t)ic*HW + seg*8);
  }
  __syncthreads();
  short8 bfr[7];
  #pragma unroll
  for (int pxt = 0; pxt < 7; ++pxt)
    #pragma unroll
    for (int j = 0; j < 8; ++j)
      bfr[pxt][j] = (short)xs[(quad*8 + j)*456 + wbase + pxt*16 + l15];
  const float* xg = x + (size_t)(b*512 + g*128)*HW + h0*56;
  float* og = out + (size_t)(b*512 + g*128)*HW + h0*56;
  #pragma unroll
  for (int oct = 0; oct < 8; ++oct){
    short8 afr = pack8(w3 + (size_t)(g*128 + oct*16 + l15)*32 + quad*8);  // fp32 [oc][ic32]
    floatx4 acc[7] = {};
    #pragma unroll
    for (int pxt = 0; pxt < 7; ++pxt)
      acc[pxt] = __builtin_amdgcn_mfma_f32_16x16x32_bf16(afr, bfr[pxt], acc[pxt], 0,0,0);
    #pragma unroll
    for (int reg = 0; reg < 4; ++reg){
      int oc = oct*16 + quad*4 + reg;
      float sc = bn[512 + g*128 + oc], sh = bn[1024 + g*128 + oc];
      #pragma unroll
      for (int pxt = 0; pxt < 7; ++pxt){
        size_t o2 = (size_t)oc*HW + wbase + pxt*16 + l15;
        og[o2] = fmaxf(sc*acc[pxt][reg] + sh + xg[o2], 0.0f);
      }
    }
  }
}

// ---------------------------------------------------------------------------
extern "C" void kernel_launch(void* const* d_in, const int* in_sizes, int n_in,
                              void* d_out, int out_size, void* d_ws, size_t ws_size,
                              hipStream_t stream){
  const float* x    = (const float*)d_in[0];
  const float* mask = (const float*)d_in[1];
  const float* w1   = (const float*)d_in[2];
  const float* g1   = (const float*)d_in[3];
  const float* b1   = (const float*)d_in[4];
  const float* m1   = (const float*)d_in[5];
  const float* v1   = (const float*)d_in[6];
  const float* w2   = (const float*)d_in[7];
  const float* g2   = (const float*)d_in[8];
  const float* b2   = (const float*)d_in[9];
  const float* m2   = (const float*)d_in[10];
  const float* v2   = (const float*)d_in[11];
  const float* w3   = (const float*)d_in[12];
  const float* g3   = (const float*)d_in[13];
  const float* b3   = (const float*)d_in[14];
  const float* m3   = (const float*)d_in[15];
  const float* v3   = (const float*)d_in[16];

  char* ws = (char*)d_ws;
  U16*   w2t = (U16*)ws;                               //      0 .. 73,728
  float* bn  = (float*)(ws + 73728);                   // 73,728 .. 79,872
  U16*   t1  = (U16*)(ws + 79872);                     // 12,845,056 B
  U16*   t2  = (U16*)(ws + 79872 + 12845056);          // 12,845,056 B (total ~24.6 MB)

  k_pre<<<147, 256, 0, stream>>>(w2, g1,b1,m1,v1, g2,b2,m2,v2, g3,b3,m3,v3, w2t, bn);
  dim3 grid(7, 4, 16);   // (mh strip, group, batch)
  k_conv1<<<grid, 256, 0, stream>>>(x, mask, w1, bn, t1);
  k_conv2<<<grid, 256, 0, stream>>>(t1, mask, w2t, bn, t2);
  k_conv3<<<grid, 256, 0, stream>>>(t2, x, w3, bn, (float*)d_out);
}

// Round 3
// 270.681 us; speedup vs baseline: 1.3060x; 1.0705x over previous
//
#include <hip/hip_runtime.h>
#include <stdint.h>

typedef unsigned short U16;
typedef unsigned int   U32;
typedef __attribute__((ext_vector_type(8))) short short8;   // 8 bf16 = 4 VGPRs (MFMA A/B frag)
typedef __attribute__((ext_vector_type(4))) float floatx4;  // MFMA C/D frag

#define HW 3136   // 56*56

__device__ __forceinline__ U16 f2b(float f){
    union { float f; unsigned int i; } v; v.f = f;
    unsigned int u = (v.i + 0x7FFFu + ((v.i >> 16) & 1u)) >> 16;  // RNE
    return (U16)u;
}
// load 8 consecutive fp32, round to bf16, return as MFMA 8x-bf16 fragment
__device__ __forceinline__ short8 pack8(const float* p){
    float4 a = *reinterpret_cast<const float4*>(p);
    float4 b = *reinterpret_cast<const float4*>(p + 4);
    short8 r;
    r[0]=(short)f2b(a.x); r[1]=(short)f2b(a.y); r[2]=(short)f2b(a.z); r[3]=(short)f2b(a.w);
    r[4]=(short)f2b(b.x); r[5]=(short)f2b(b.y); r[6]=(short)f2b(b.z); r[7]=(short)f2b(b.w);
    return r;
}

// ---------------------------------------------------------------------------
// k_pre: fold BN into fp32 scale/shift; transpose+convert w2 (fp32) ->
// bf16 [g][tap][oc 32][ic 32].
// bn layout (fp32): [0:128) s1 [128:256) sh1 [256:384) s2 [384:512) sh2
//                   [512:1024) s3 [1024:1536) sh3
// ---------------------------------------------------------------------------
__global__ void k_pre(const float* __restrict__ w2,
                      const float* g1, const float* b1, const float* m1, const float* v1,
                      const float* g2, const float* b2, const float* m2, const float* v2,
                      const float* g3, const float* b3, const float* m3, const float* v3,
                      U16* __restrict__ w2t, float* __restrict__ bn){
  int i = blockIdx.x * 256 + threadIdx.x;
  if (i < 4*9*32*32) {
    int ic  = i & 31;
    int oc  = (i >> 5) & 31;
    int gt  = i >> 10;          // g*9 + tap
    int g_  = gt / 9, tap = gt % 9;
    w2t[i] = f2b(w2[((g_*32 + oc)*32 + ic)*9 + tap]);
  } else {
    int j = i - 4*9*32*32;
    if (j >= 768) return;
    const float *gp, *bp, *mp, *vp; int c, so, sho;
    if (j < 128)      { c = j;       gp=g1; bp=b1; mp=m1; vp=v1; so = 0;   sho = 128;  }
    else if (j < 256) { c = j - 128; gp=g2; bp=b2; mp=m2; vp=v2; so = 256; sho = 384;  }
    else              { c = j - 256; gp=g3; bp=b3; mp=m3; vp=v3; so = 512; sho = 1024; }
    float s = gp[c] / sqrtf(vp[c] + 1e-5f);
    bn[so + c]  = s;
    bn[sho + c] = bp[c] - mp[c] * s;
  }
}

// ---------------------------------------------------------------------------
// k_conv1: t1 = mask * relu(bn1(conv1x1_g(mask * x)))   (512 -> 128, G=4)
// STRIP, 512 thr / 8 waves: wave = (oct, px-quarter). Staging shared via LDS.
// ---------------------------------------------------------------------------
__global__ __launch_bounds__(512) void k_conv1(const float* __restrict__ x,
        const float* __restrict__ mask, const float* __restrict__ w1,
        const float* __restrict__ bn, U16* __restrict__ t1){
  const int t = threadIdx.x;
  const int lane = t & 63, wave = t >> 6;          // wave 0..7
  const int quad = lane >> 4, l15 = lane & 15;
  const int oct = wave & 1, pxq = wave >> 1;       // oct 0..1, px-quarter 0..3
  const int b = blockIdx.z, g = blockIdx.y, mh = blockIdx.x;
  const int h0 = mh*8, wbase = pxq*112;
  __shared__ float mk[7];
  __shared__ __align__(16) U16 xs[32*456];
  if (t < 7) mk[t] = mask[((b*4 + g)*7 + mh)*7 + t];
  const float* xg = x + (size_t)(b*512 + g*128)*HW + h0*56;
  U16* t1g = t1 + (size_t)(b*128 + g*32)*HW + h0*56;

  // A fragments: w1 fp32 [oc(g*32..)][ic 128]; this wave's oct only
  const float* wg = w1 + (size_t)(g*32)*128;
  short8 afr[4];
  #pragma unroll
  for (int ks = 0; ks < 4; ++ks)
    afr[ks] = pack8(wg + (oct*16 + l15)*128 + ks*32 + quad*8);

  floatx4 acc[7] = {};
  #pragma unroll
  for (int ch = 0; ch < 4; ++ch){
    __syncthreads();   // ch=0: guards mk; ch>0: guards xs reuse
    #pragma unroll
    for (int k = 0; k < 7; ++k){
      int idx = k*512 + t;                 // 3584 float4 = 32 ic x 112
      int ic = idx / 112, f = idx - ic*112;
      int px = f*4;                        // 4 cols, never crosses an 8-col cell
      float4 v = *reinterpret_cast<const float4*>(xg + (size_t)(ch*32 + ic)*HW + px);
      float m = mk[(px % 56) >> 3];
      U32 lo = (U32)f2b(v.x*m) | ((U32)f2b(v.y*m) << 16);
      U32 hi = (U32)f2b(v.z*m) | ((U32)f2b(v.w*m) << 16);
      *reinterpret_cast<uint2*>(&xs[ic*456 + px]) = make_uint2(lo, hi);
    }
    __syncthreads();
    #pragma unroll
    for (int pxt = 0; pxt < 7; ++pxt){
      short8 bfr;
      #pragma unroll
      for (int j = 0; j < 8; ++j)
        bfr[j] = (short)xs[(quad*8 + j)*456 + wbase + pxt*16 + l15];
      acc[pxt] = __builtin_amdgcn_mfma_f32_16x16x32_bf16(afr[ch], bfr, acc[pxt], 0,0,0);
    }
  }
  #pragma unroll
  for (int reg = 0; reg < 4; ++reg){
    int oc = oct*16 + quad*4 + reg;
    float sc = bn[g*32 + oc], sh = bn[128 + g*32 + oc];
    #pragma unroll
    for (int pxt = 0; pxt < 7; ++pxt){
      int px = wbase + pxt*16 + l15;
      float y = fmaxf(sc*acc[pxt][reg] + sh, 0.0f) * mk[(px % 56) >> 3];
      t1g[(size_t)oc*HW + px] = f2b(y);    // masked cells: exact 0
    }
  }
}

// ---------------------------------------------------------------------------
// k_conv2: t2 = mask * relu(bn2(conv3x3_g(t1)))   (128 -> 128, G=4, pad 1)
// STRIP, 512 thr / 8 waves: wave = (oct, row-quarter).
// LDS: [32 ic][10 r][72 c] bf16, data cols at 8..63, halo cols 7 and 64.
// ---------------------------------------------------------------------------
__global__ __launch_bounds__(512) void k_conv2(const U16* __restrict__ t1,
        const float* __restrict__ mask, const U16* __restrict__ w2t,
        const float* __restrict__ bn, U16* __restrict__ t2){
  const int t = threadIdx.x;
  const int lane = t & 63, wave = t >> 6;          // wave 0..7
  const int quad = lane >> 4, l15 = lane & 15;
  const int oct = wave & 1, rq = wave >> 1;        // oct 0..1, row-quarter 0..3
  const int b = blockIdx.z, g = blockIdx.y, mh = blockIdx.x;
  const int h0 = mh*8;
  __shared__ float mk[7];
  __shared__ __align__(16) U16 s[32*720];
  if (t < 7) mk[t] = mask[((b*4 + g)*7 + mh)*7 + t];
  if (t < 320){                            // zero halo cols (c=-1, c=56), all 320
    int ic = t / 10, r = t - ic*10;
    s[(ic*10 + r)*72 + 7]  = 0;
    s[(ic*10 + r)*72 + 64] = 0;
  }
  const U16* tg = t1 + (size_t)(b*128 + g*32)*HW;
  #pragma unroll
  for (int k = 0; k < 5; ++k){
    int idx = k*512 + t;                   // 2240 uint4 = 32 ic x 10 r x 7 seg
    if (idx < 2240){
      int ic = idx / 70, rem = idx - ic*70;
      int r = rem / 7, seg = rem - r*7;
      int hh = h0 - 1 + r;
      uint4 v = make_uint4(0,0,0,0);
      if (hh >= 0 && hh < 56)
        v = *reinterpret_cast<const uint4*>(tg + (size_t)ic*HW + hh*56 + seg*8);
      *reinterpret_cast<uint4*>(&s[(ic*10 + r)*72 + 8 + seg*8]) = v;
    }
  }
  __syncthreads();
  const U16* wg = w2t + g*9*32*32;         // bf16 [tap][oc][ic]
  floatx4 acc[7] = {};
  #pragma unroll
  for (int kh = 0; kh < 3; ++kh){
    const int lr = rq*2 + (l15 >> 3) + kh;         // 0..9
    #pragma unroll
    for (int kw = 0; kw < 3; ++kw){
      int tap = kh*3 + kw;
      short8 a0 = *reinterpret_cast<const short8*>(wg + (tap*32 + oct*16 + l15)*32 + quad*8);
      #pragma unroll
      for (int pxt = 0; pxt < 7; ++pxt){
        int lc = 7 + pxt*8 + (l15 & 7) + kw;       // global col + 8 + (kw-1)
        short8 bfr;
        #pragma unroll
        for (int j = 0; j < 8; ++j)
          bfr[j] = (short)s[((quad*8 + j)*10 + lr)*72 + lc];
        acc[pxt] = __builtin_amdgcn_mfma_f32_16x16x32_bf16(a0, bfr, acc[pxt], 0,0,0);
      }
    }
  }
  U16* og = t2 + (size_t)(b*128 + g*32)*HW + h0*56;
  const int pr = rq*2 + (l15 >> 3);
  #pragma unroll
  for (int reg = 0; reg < 4; ++reg){
    int oc = oct*16 + quad*4 + reg;
    float sc = bn[256 + g*32 + oc], sh = bn[384 + g*32 + oc];
    #pragma unroll
    for (int pxt = 0; pxt < 7; ++pxt){
      float y = fmaxf(sc*acc[pxt][reg] + sh, 0.0f) * mk[pxt];
      og[oc*HW + pr*56 + pxt*8 + (l15 & 7)] = f2b(y);   // masked: exact 0
    }
  }
}

// ---------------------------------------------------------------------------
// k_conv3: out = relu(bn3(conv1x1_g(t2)) + x)   (128 -> 512, G=4), fp32 out.
// STRIP, 1024 thr / 16 waves: wave = (oct-pair, px-quarter); each wave does
// 2 of 8 octs over its 112-px quarter. Residual reads/writes are aligned
// 64B segments.
// ---------------------------------------------------------------------------
__global__ __launch_bounds__(1024) void k_conv3(const U16* __restrict__ t2,
        const float* __restrict__ x, const float* __restrict__ w3,
        const float* __restrict__ bn, float* __restrict__ out){
  const int t = threadIdx.x;
  const int lane = t & 63, wave = t >> 6;          // wave 0..15
  const int quad = lane >> 4, l15 = lane & 15;
  const int pxq = wave & 3, ocp = wave >> 2;       // px-quarter 0..3, oct-pair 0..3
  const int b = blockIdx.z, g = blockIdx.y, mh = blockIdx.x;
  const int h0 = mh*8, wbase = pxq*112;
  __shared__ __align__(16) U16 xs[32*456];
  const U16* tg = t2 + (size_t)(b*128 + g*32)*HW + h0*56;
  #pragma unroll
  for (int k = 0; k < 2; ++k){
    int idx = k*1024 + t;                  // 1792 uint4 = 32 ic x 56 seg
    if (idx < 1792){
      int ic = idx / 56, seg = idx - ic*56;
      *reinterpret_cast<uint4*>(&xs[ic*456 + seg*8]) =
          *reinterpret_cast<const uint4*>(tg + (size_t)ic*HW + seg*8);
    }
  }
  __syncthreads();
  short8 bfr[7];
  #pragma unroll
  for (int pxt = 0; pxt < 7; ++pxt)
    #pragma unroll
    for (int j = 0; j < 8; ++j)
      bfr[pxt][j] = (short)xs[(quad*8 + j)*456 + wbase + pxt*16 + l15];
  const float* xg = x + (size_t)(b*512 + g*128)*HW + h0*56;
  float* og = out + (size_t)(b*512 + g*128)*HW + h0*56;
  #pragma unroll
  for (int o2 = 0; o2 < 2; ++o2){
    const int oct = ocp*2 + o2;
    short8 afr = pack8(w3 + (size_t)(g*128 + oct*16 + l15)*32 + quad*8);  // fp32 [oc][ic32]
    floatx4 acc[7] = {};
    #pragma unroll
    for (int pxt = 0; pxt < 7; ++pxt)
      acc[pxt] = __builtin_amdgcn_mfma_f32_16x16x32_bf16(afr, bfr[pxt], acc[pxt], 0,0,0);
    #pragma unroll
    for (int reg = 0; reg < 4; ++reg){
      int oc = oct*16 + quad*4 + reg;
      float sc = bn[512 + g*128 + oc], sh = bn[1024 + g*128 + oc];
      #pragma unroll
      for (int pxt = 0; pxt < 7; ++pxt){
        size_t o2i = (size_t)oc*HW + wbase + pxt*16 + l15;
        og[o2i] = fmaxf(sc*acc[pxt][reg] + sh + xg[o2i], 0.0f);
      }
    }
  }
}

// ---------------------------------------------------------------------------
extern "C" void kernel_launch(void* const* d_in, const int* in_sizes, int n_in,
                              void* d_out, int out_size, void* d_ws, size_t ws_size,
                              hipStream_t stream){
  const float* x    = (const float*)d_in[0];
  const float* mask = (const float*)d_in[1];
  const float* w1   = (const float*)d_in[2];
  const float* g1   = (const float*)d_in[3];
  const float* b1   = (const float*)d_in[4];
  const float* m1   = (const float*)d_in[5];
  const float* v1   = (const float*)d_in[6];
  const float* w2   = (const float*)d_in[7];
  const float* g2   = (const float*)d_in[8];
  const float* b2   = (const float*)d_in[9];
  const float* m2   = (const float*)d_in[10];
  const float* v2   = (const float*)d_in[11];
  const float* w3   = (const float*)d_in[12];
  const float* g3   = (const float*)d_in[13];
  const float* b3   = (const float*)d_in[14];
  const float* m3   = (const float*)d_in[15];
  const float* v3   = (const float*)d_in[16];

  char* ws = (char*)d_ws;
  U16*   w2t = (U16*)ws;                               //      0 .. 73,728
  float* bn  = (float*)(ws + 73728);                   // 73,728 .. 79,872
  U16*   t1  = (U16*)(ws + 79872);                     // 12,845,056 B
  U16*   t2  = (U16*)(ws + 79872 + 12845056);          // 12,845,056 B (total ~24.6 MB)

  k_pre<<<147, 256, 0, stream>>>(w2, g1,b1,m1,v1, g2,b2,m2,v2, g3,b3,m3,v3, w2t, bn);
  dim3 grid(7, 4, 16);   // (mh strip, group, batch)
  k_conv1<<<grid, 512, 0, stream>>>(x, mask, w1, bn, t1);
  k_conv2<<<grid, 512, 0, stream>>>(t1, mask, w2t, bn, t2);
  k_conv3<<<grid, 1024, 0, stream>>>(t2, x, w3, bn, (float*)d_out);
}